// Round 7
// baseline (571.981 us; speedup 1.0000x reference)
//
#include <hip/hip_runtime.h>
#include <hip/hip_bf16.h>
#include <hip/hip_cooperative_groups.h>

#define BATCH 2048
#define IN_DIM 128
#define GRIDN 128
#define HID 256
#define DEPTH 7

typedef unsigned int u32;
typedef __attribute__((ext_vector_type(8))) short short8;
typedef __attribute__((ext_vector_type(4))) float floatx4;

// ---------------- ws layout (bytes) ----------------
// fs2: bf16, MFMA-frag-ordered: [slab:896][nhalf:2][ks:4][tt:8][l4:4][l15:16][g8:8]
#define OFF_FST   ((size_t)0)
#define SZ_FST    ((size_t)7*128*256*128*2)       // 58,720,256
#define OFF_ZT    (OFF_FST + SZ_FST)              // fp32 z_t [128][2048]
#define SZ_ZT     ((size_t)BATCH*IN_DIM*4)
#define OFF_HPRE  (OFF_ZT + SZ_ZT)                // fp32 h_pre [2048][256]
#define SZ_HPRE   ((size_t)BATCH*HID*4)
#define OFF_STATS (OFF_HPRE + SZ_HPRE)            // fp32 stats 3*[512]
#define SZ_STATS  ((size_t)3*2*HID*4)

__device__ __forceinline__ u32 pack2_bf16(float lo, float hi) {
  __hip_bfloat162 b2;
  b2.x = __float2bfloat16(lo);
  b2.y = __float2bfloat16(hi);
  return *reinterpret_cast<u32*>(&b2);
}

// truncating bf16x2 pack: one v_perm_b32 (lo = hi16(a), hi = hi16(b))
__device__ __forceinline__ u32 pk_trunc(float a, float b) {
  return __builtin_amdgcn_perm(__float_as_uint(b), __float_as_uint(a), 0x07060302u);
}

__device__ __forceinline__ float gelu_exact(float x) {
  return 0.5f * x * (1.0f + erff(x * 0.70710678118654752f));
}

// ---------------- prep: per-feature min/max + z_t + zero h_pre/stats ----------------
// one block per feature i (128 blocks); no cross-block dependencies at all.
__global__ void prep_kernel(const float* __restrict__ x,
                            float* __restrict__ z_t,
                            float* __restrict__ h_pre,
                            float* __restrict__ stats) {
  int i = blockIdx.x, t = threadIdx.x;
  float v[8];
  float mn = 1e30f, mx = -1e30f;
#pragma unroll
  for (int j = 0; j < 8; ++j) {
    v[j] = x[(size_t)(t + j * 256) * IN_DIM + i];
    mn = fminf(mn, v[j]); mx = fmaxf(mx, v[j]);
  }
  __shared__ float smn[256], smx[256];
  smn[t] = mn; smx[t] = mx;
  __syncthreads();
  for (int s = 128; s > 0; s >>= 1) {
    if (t < s) { smn[t] = fminf(smn[t], smn[t + s]); smx[t] = fmaxf(smx[t], smx[t + s]); }
    __syncthreads();
  }
  float lo = smn[0];
  float inv = 1.0f / (smx[0] - lo + 1e-6f);
#pragma unroll
  for (int j = 0; j < 8; ++j)
    z_t[(size_t)i * BATCH + t + j * 256] = (v[j] - lo) * inv;
  // zero this block's slice of h_pre (2 MB / 128 = 16 KB) + stats
  float4 zz = make_float4(0.f, 0.f, 0.f, 0.f);
  float4* hz = (float4*)(h_pre + (size_t)i * 4096);
#pragma unroll
  for (int q = 0; q < 4; ++q) hz[q * 256 + t] = zz;
  if (i == 0) {
    for (int q = t; q < 1536; q += 256) stats[q] = 0.f;
  }
}

// ---------------- fs fp32 [d,i,g,h] -> c_d*bf16, MFMA-frag-ordered fs2 ----------------
// cw computed inline (7 exps/thread) -> no dependency on any other kernel.
__global__ void convert_kernel(const float* __restrict__ fs,
                               const float* __restrict__ depth_scores,
                               __hip_bfloat16* __restrict__ fs2) {
  __shared__ u32 lds[256 * 33];   // [h][33] u32 rows: +1 pad
  int slab = blockIdx.x;          // d*128 + i
  int t = threadIdx.x;
  int d = slab >> 7;
  float m = -1e30f;
#pragma unroll
  for (int d0 = 0; d0 < DEPTH; ++d0) m = fmaxf(m, depth_scores[d0]);
  float sum = 0.f, num = 0.f;
#pragma unroll
  for (int d0 = 0; d0 < DEPTH; ++d0) {
    float e = expf(depth_scores[d0] - m);
    sum += e;
    if (d0 >= d) num += e;
  }
  float cd = num / sum;

  const float* src = fs + (size_t)slab * (GRIDN * HID);
  char* dstb = (char*)fs2 + (size_t)slab * 65536;

  for (int gh = 0; gh < 2; ++gh) {
    const float* s0 = src + (size_t)gh * 64 * HID + t;
#pragma unroll
    for (int g2 = 0; g2 < 32; ++g2) {
      float va = s0[(size_t)(2 * g2) * HID];
      float vb = s0[(size_t)(2 * g2 + 1) * HID];
      lds[t * 33 + g2] = pack2_bf16(cd * va, cd * vb);
    }
    __syncthreads();
#pragma unroll
    for (int it2 = 0; it2 < 8; ++it2) {
      int task = t + it2 * 256;         // [0,2048) = 32KB of this gh-half
      int c = task >> 9;                // [0,4): nhalf*2 + ksl
      int q = task & 511;
      int nhalf = c >> 1, ksl = c & 1;
      int tt = q >> 6, l4 = (q >> 4) & 3, l15 = q & 15;
      int h = nhalf * 128 + tt * 16 + l15;
      int mm = ksl * 4 + l4;
      u32 a0 = lds[h * 33 + mm * 4 + 0];
      u32 a1 = lds[h * 33 + mm * 4 + 1];
      u32 a2 = lds[h * 33 + mm * 4 + 2];
      u32 a3 = lds[h * 33 + mm * 4 + 3];
      size_t off = (size_t)nhalf * 32768 + (size_t)(gh * 2 + ksl) * 8192 +
                   (size_t)tt * 1024 + l4 * 256 + l15 * 16;
      *(uint4*)(dstb + off) = make_uint4(a0, a1, a2, a3);
    }
    __syncthreads();
  }
}

// ---------------- big GEMM: h_pre += relu(z-grids) @ (c_d*fs) ----------------
// LDS-free, barrier-free, all-register pipeline:
//   - B frags loaded global->VGPR directly (frag-ordered fs2 -> each dwordx4
//     is one 1KB single-segment wave transaction); double-buffered at 4-frag
//     granularity (prefetch distance = 16 MFMAs >= L2 latency).
//   - g double-buffered per ks; z double-buffered per slab; A generated in
//     registers with pk_trunc. Compiler emits precise per-reg waitcnts.
// Wave tile 64Mx128N; block 256 thr = 4 waves (2m x 2n) = 128x256 tile.
// Grid: 16 mtiles x 32 K-chunks (28 slabs) = 512 blocks = 2/CU, XCD-swizzled.
__launch_bounds__(256, 2)
__global__ void gemm_kernel(const float* __restrict__ z_t,
                            const float* __restrict__ grids,
                            const __hip_bfloat16* __restrict__ fs2,
                            float* __restrict__ h_pre) {
  int bx = blockIdx.x;
  int xcd = bx & 7;
  int t6 = bx >> 3;                 // [0,64)
  int cg = t6 >> 4;                 // [0,4)
  int jb = t6 & 15;                 // [0,16) mtile(128)
  int chunk = xcd + 8 * cg;         // [0,32); same-XCD blocks share fs2 chunk
  int slab0 = chunk * 28;

  int tid = threadIdx.x;
  int w = tid >> 6, l = tid & 63;
  int l15 = l & 15, l4 = l >> 4;
  int wm = w >> 1, wn = w & 1;
  int mbase = jb * 128 + wm * 64;
  int nbase = wn * 128;

  floatx4 acc[4][8];
#pragma unroll
  for (int a = 0; a < 4; ++a)
#pragma unroll
    for (int b = 0; b < 8; ++b) acc[a][b] = (floatx4)0.f;

  const char* bptr = (const char*)fs2 + (size_t)slab0 * 65536 + (size_t)wn * 32768 +
                     (size_t)l * 16;

  short8 bf[2][4];
  float zv[2][4];
  float4 g0[2], g1[2];

  auto loadB = [&](int sub, int p) {
    const char* src = bptr + (size_t)(sub >> 3) * 65536 + (size_t)((sub >> 1) & 3) * 8192 +
                      (size_t)(sub & 1) * 4096;
    bf[p][0] = *(const short8*)(src);
    bf[p][1] = *(const short8*)(src + 1024);
    bf[p][2] = *(const short8*)(src + 2048);
    bf[p][3] = *(const short8*)(src + 3072);
  };
  auto loadZ = [&](int s, int p) {
    int iz = (slab0 + s) & 127;
    const float* zp = z_t + (size_t)iz * BATCH + mbase + l15;
    zv[p][0] = zp[0]; zv[p][1] = zp[16]; zv[p][2] = zp[32]; zv[p][3] = zp[48];
  };
  auto loadG = [&](int s, int ks, int p) {
    const float* gp = grids + (size_t)(slab0 + s) * GRIDN + ks * 32 + l4 * 8;
    g0[p] = *(const float4*)gp;
    g1[p] = *(const float4*)(gp + 4);
  };

  loadB(0, 0);
  loadZ(0, 0);
  loadG(0, 0, 0);

#pragma unroll 1
  for (int s = 0; s < 28; ++s) {
    int sp = s & 1;
#pragma unroll
    for (int ks = 0; ks < 4; ++ks) {
      int kp = (s * 4 + ks) & 1;
      // prefetch next ks's grid row (clamped at end; redundant load is harmless)
      {
        int nn = s * 4 + ks + 1;
        if (nn > 111) nn = 111;
        loadG(nn >> 2, nn & 3, kp ^ 1);
      }
      if (ks == 0) loadZ((s + 1 < 28) ? s + 1 : s, sp ^ 1);

      // A fragments for this ks: relu(z - grid), truncating bf16 pack
      short8 af[4];
#pragma unroll
      for (int u = 0; u < 4; ++u) {
        float zu = zv[sp][u];
        union { uint4 q; short8 s8; } pk;
        pk.q.x = pk_trunc(fmaxf(zu - g0[kp].x, 0.f), fmaxf(zu - g0[kp].y, 0.f));
        pk.q.y = pk_trunc(fmaxf(zu - g0[kp].z, 0.f), fmaxf(zu - g0[kp].w, 0.f));
        pk.q.z = pk_trunc(fmaxf(zu - g1[kp].x, 0.f), fmaxf(zu - g1[kp].y, 0.f));
        pk.q.w = pk_trunc(fmaxf(zu - g1[kp].z, 0.f), fmaxf(zu - g1[kp].w, 0.f));
        af[u] = pk.s8;
      }

#pragma unroll
      for (int grp = 0; grp < 2; ++grp) {
        int sub = (s * 4 + ks) * 2 + grp;
        int bp = sub & 1;
        int nsub = sub + 1; if (nsub > 223) nsub = 223;
        loadB(nsub, bp ^ 1);     // issue next substep's 4 frag loads first
#pragma unroll
        for (int u = 0; u < 4; ++u)
#pragma unroll
          for (int tt = 0; tt < 4; ++tt)
            acc[u][grp * 4 + tt] = __builtin_amdgcn_mfma_f32_16x16x32_bf16(
                af[u], bf[bp][tt], acc[u][grp * 4 + tt], 0, 0, 0);
      }
    }
  }

  // epilogue: atomic accumulate (C/D: col=l&15, row=(l>>4)*4+r)
  int row0 = mbase + l4 * 4;
  int col0 = nbase + l15;
#pragma unroll
  for (int u = 0; u < 4; ++u) {
#pragma unroll
    for (int tt = 0; tt < 8; ++tt) {
      int col = col0 + tt * 16;
#pragma unroll
      for (int r = 0; r < 4; ++r) {
        int row = row0 + u * 16 + r;
        atomicAdd(&h_pre[(size_t)row * HID + col], acc[u][tt][r]);
      }
    }
  }
}

// ---------------- head: full MLP (3x Linear+BN+GELU) + final dot, cooperative ----------------
// grid 256 x 256thr; BN batch stats via global atomics + grid.sync (3x).
// Intermediate activations never touch HBM (live in LDS/regs).
__global__ void head_kernel(const float* __restrict__ h_pre,
                            const float* __restrict__ mlp_W,
                            const float* __restrict__ mlp_b,
                            const float* __restrict__ bn_g,
                            const float* __restrict__ bn_b,
                            const float* __restrict__ W_out,
                            const float* __restrict__ b_out,
                            float* __restrict__ stats,
                            float* __restrict__ out) {
  cooperative_groups::grid_group grid = cooperative_groups::this_grid();
  __shared__ float Xs[8][HID];
  int br = blockIdx.x, c = threadIdx.x;
#pragma unroll
  for (int r = 0; r < 8; ++r) Xs[r][c] = h_pre[(size_t)(br * 8 + r) * HID + c];
  __syncthreads();
  float y[8];
#pragma unroll 1
  for (int j = 0; j < 3; ++j) {
    const float* W = mlp_W + (size_t)j * HID * HID;
    float acc[8] = {0.f, 0.f, 0.f, 0.f, 0.f, 0.f, 0.f, 0.f};
#pragma unroll 8
    for (int k = 0; k < HID; ++k) {
      float wv = W[(size_t)k * HID + c];
#pragma unroll
      for (int r = 0; r < 8; ++r) acc[r] += Xs[r][k] * wv;
    }
    float bb = mlp_b[j * HID + c];
    float s1 = 0.f, s2 = 0.f;
#pragma unroll
    for (int r = 0; r < 8; ++r) { y[r] = acc[r] + bb; s1 += y[r]; s2 += y[r] * y[r]; }
    atomicAdd(&stats[j * 512 + c], s1);
    atomicAdd(&stats[j * 512 + 256 + c], s2);
    grid.sync();
    float mean = stats[j * 512 + c] * (1.0f / BATCH);
    float var = stats[j * 512 + 256 + c] * (1.0f / BATCH) - mean * mean;
    float rstd = rsqrtf(var + 1e-5f);
    float gm = bn_g[j * HID + c], bt = bn_b[j * HID + c];
    // all blocks are past their matmul reads (grid.sync above) -> safe to overwrite
#pragma unroll
    for (int r = 0; r < 8; ++r) Xs[r][c] = gelu_exact((y[r] - mean) * rstd * gm + bt);
    __syncthreads();
  }
  // final: out = Xs @ W_out + b_out
  float wo = W_out[c];
  float bo = b_out[0];
  __shared__ float red[4];
  int wv_ = c >> 6, lane = c & 63;
#pragma unroll 1
  for (int r = 0; r < 8; ++r) {
    float v = Xs[r][c] * wo;
#pragma unroll
    for (int off = 32; off > 0; off >>= 1) v += __shfl_down(v, off);
    if (lane == 0) red[wv_] = v;
    __syncthreads();
    if (c == 0) out[br * 8 + r] = red[0] + red[1] + red[2] + red[3] + bo;
    __syncthreads();
  }
}

extern "C" void kernel_launch(void* const* d_in, const int* in_sizes, int n_in,
                              void* d_out, int out_size, void* d_ws, size_t ws_size,
                              hipStream_t stream) {
  const float* x      = (const float*)d_in[0];
  const float* grids  = (const float*)d_in[1];
  const float* fs     = (const float*)d_in[2];
  const float* dscore = (const float*)d_in[3];
  const float* mlp_W  = (const float*)d_in[4];
  const float* mlp_b  = (const float*)d_in[5];
  const float* bn_g   = (const float*)d_in[6];
  const float* bn_b   = (const float*)d_in[7];
  const float* W_out  = (const float*)d_in[8];
  const float* b_out  = (const float*)d_in[9];
  float* out = (float*)d_out;

  char* ws = (char*)d_ws;
  __hip_bfloat16* fs2 = (__hip_bfloat16*)(ws + OFF_FST);
  float* z_t   = (float*)(ws + OFF_ZT);
  float* h_pre = (float*)(ws + OFF_HPRE);
  float* stats = (float*)(ws + OFF_STATS);

  prep_kernel<<<128, 256, 0, stream>>>(x, z_t, h_pre, stats);
  convert_kernel<<<DEPTH * IN_DIM, 256, 0, stream>>>(fs, dscore, fs2);
  gemm_kernel<<<512, 256, 0, stream>>>(z_t, grids, fs2, h_pre);

  const float* hp = h_pre;
  float* st = stats;
  void* hargs[] = {(void*)&hp, (void*)&mlp_W, (void*)&mlp_b, (void*)&bn_g,
                   (void*)&bn_b, (void*)&W_out, (void*)&b_out, (void*)&st,
                   (void*)&out};
  hipLaunchCooperativeKernel((void*)head_kernel, dim3(256), dim3(256), hargs, 0, stream);
}

// Round 8
// 481.039 us; speedup vs baseline: 1.1891x; 1.1891x over previous
//
#include <hip/hip_runtime.h>
#include <hip/hip_bf16.h>

#define BATCH 2048
#define IN_DIM 128
#define GRIDN 128
#define HID 256
#define DEPTH 7

typedef unsigned int u32;
typedef __attribute__((ext_vector_type(8))) short short8;
typedef __attribute__((ext_vector_type(4))) float floatx4;

// ---------------- ws layout (bytes) ----------------
// fs2: bf16, MFMA-frag-ordered: [slab:896][nhalf:2][ks:4][tt:8][l4:4][l15:16][g8:8]
#define OFF_FST   ((size_t)0)
#define SZ_FST    ((size_t)7*128*256*128*2)       // 58,720,256
#define OFF_ZT    (OFF_FST + SZ_FST)              // fp32 z_t [128][2048]
#define SZ_ZT     ((size_t)BATCH*IN_DIM*4)
#define OFF_HPRE  (OFF_ZT + SZ_ZT)                // fp32 h_pre [2048][256]
#define SZ_HPRE   ((size_t)BATCH*HID*4)
#define OFF_STATS (OFF_HPRE + SZ_HPRE)            // fp32 stats 3*[512]
#define SZ_STATS  ((size_t)3*2*HID*4)
#define OFF_KEYS  (OFF_STATS + SZ_STATS)          // u32 keys [256]
#define SZ_KEYS   ((size_t)256*4)
#define OFF_CW    (OFF_KEYS + SZ_KEYS)            // fp32 cw[7] (+pad)
#define SZ_CW     ((size_t)32)

__device__ __forceinline__ u32 pack2_bf16(float lo, float hi) {
  __hip_bfloat162 b2;
  b2.x = __float2bfloat16(lo);
  b2.y = __float2bfloat16(hi);
  return *reinterpret_cast<u32*>(&b2);
}

// truncating bf16x2 pack: one v_perm_b32 (lo = hi16(a), hi = hi16(b))
__device__ __forceinline__ u32 pk_trunc(float a, float b) {
  return __builtin_amdgcn_perm(__float_as_uint(b), __float_as_uint(a), 0x07060302u);
}

__device__ __forceinline__ float gelu_exact(float x) {
  return 0.5f * x * (1.0f + erff(x * 0.70710678118654752f));
}

// ---------------- prep1: per-feature min/max via monotone-key atomics + cw
__global__ void prep1_kernel(const float* __restrict__ x, u32* __restrict__ keys,
                             const float* __restrict__ depth_scores,
                             float* __restrict__ cw) {
  int t = threadIdx.x;
  int base = blockIdx.x * 256 + t;
  float mn = 1e30f, mx = -1e30f;
#pragma unroll
  for (int j = 0; j < 16; ++j) {
    float v = x[base + j * 16384];   // 16384 % 128 == 0 -> same feature i each iter
    mn = fminf(mn, v); mx = fmaxf(mx, v);
  }
  __shared__ float smn[256], smx[256];
  smn[t] = mn; smx[t] = mx;
  __syncthreads();
  if (t < 128) {
    mn = fminf(smn[t], smn[t + 128]);
    mx = fmaxf(smx[t], smx[t + 128]);
    int i = base & 127;  // == t
    atomicMax(&keys[i], 0x7FFFFFFFu - __float_as_uint(mn));
    atomicMax(&keys[128 + i], __float_as_uint(mx));
  }
  if (blockIdx.x == 0 && t == 0) {
    float m = -1e30f;
    for (int d0 = 0; d0 < DEPTH; ++d0) m = fmaxf(m, depth_scores[d0]);
    float e[DEPTH]; float sum = 0.f;
    for (int d0 = 0; d0 < DEPTH; ++d0) { e[d0] = expf(depth_scores[d0] - m); sum += e[d0]; }
    float cacc = 0.f; float cs[DEPTH];
    for (int d0 = DEPTH - 1; d0 >= 0; --d0) { cacc += e[d0] / sum; cs[d0] = cacc; }
    for (int d0 = 0; d0 < DEPTH; ++d0) cw[d0] = cs[d0];
  }
}

// ---------------- prep2: z_t[i][b] via LDS transpose (256B contiguous stores)
__global__ void prep2_kernel(const float* __restrict__ x, const u32* __restrict__ keys,
                             float* __restrict__ z_t) {
  __shared__ float lds[128 * 65];
  int t = threadIdx.x;
  int b0 = blockIdx.x * 64;
#pragma unroll
  for (int q = 0; q < 32; ++q) {
    int idx = q * 256 + t;              // [0, 8192)
    int b = idx >> 7, i = idx & 127;
    lds[i * 65 + b] = x[(size_t)(b0 + b) * IN_DIM + i];
  }
  __syncthreads();
#pragma unroll
  for (int q = 0; q < 32; ++q) {
    int idx = q * 256 + t;
    int ii = idx >> 6, bb = idx & 63;
    float mnv = __uint_as_float(0x7FFFFFFFu - keys[ii]);
    float mxv = __uint_as_float(keys[128 + ii]);
    float v = (lds[ii * 65 + bb] - mnv) * (1.0f / (mxv - mnv + 1e-6f));
    z_t[(size_t)ii * BATCH + b0 + bb] = v;
  }
}

// ---------------- fs fp32 [d,i,g,h] -> c_d*bf16, MFMA-frag-ordered fs2 ----------------
__global__ void convert_kernel(const float* __restrict__ fs,
                               const float* __restrict__ cw,
                               __hip_bfloat16* __restrict__ fs2) {
  __shared__ u32 lds[256 * 33];   // [h][33] u32 rows: +1 pad
  int slab = blockIdx.x;          // d*128 + i
  int t = threadIdx.x;
  float cd = cw[slab >> 7];
  const float* src = fs + (size_t)slab * (GRIDN * HID);
  char* dstb = (char*)fs2 + (size_t)slab * 65536;

  for (int gh = 0; gh < 2; ++gh) {
    const float* s0 = src + (size_t)gh * 64 * HID + t;
#pragma unroll
    for (int g2 = 0; g2 < 32; ++g2) {
      float va = s0[(size_t)(2 * g2) * HID];
      float vb = s0[(size_t)(2 * g2 + 1) * HID];
      lds[t * 33 + g2] = pack2_bf16(cd * va, cd * vb);
    }
    __syncthreads();
#pragma unroll
    for (int it2 = 0; it2 < 8; ++it2) {
      int task = t + it2 * 256;         // [0,2048) = 32KB of this gh-half
      int c = task >> 9;                // [0,4): nhalf*2 + ksl
      int q = task & 511;
      int nhalf = c >> 1, ksl = c & 1;
      int tt = q >> 6, l4 = (q >> 4) & 3, l15 = q & 15;
      int h = nhalf * 128 + tt * 16 + l15;
      int mm = ksl * 4 + l4;
      u32 a0 = lds[h * 33 + mm * 4 + 0];
      u32 a1 = lds[h * 33 + mm * 4 + 1];
      u32 a2 = lds[h * 33 + mm * 4 + 2];
      u32 a3 = lds[h * 33 + mm * 4 + 3];
      size_t off = (size_t)nhalf * 32768 + (size_t)(gh * 2 + ksl) * 8192 +
                   (size_t)tt * 1024 + l4 * 256 + l15 * 16;
      *(uint4*)(dstb + off) = make_uint4(a0, a1, a2, a3);
    }
    __syncthreads();
  }
}

// ---------------- big GEMM: h_pre += relu(z-grids) @ (c_d*fs) ----------------
// LDS-free, barrier-free, all-register pipeline with COMPILE-TIME buffer
// parity (ks fully unrolled; bfA/bfB, gA/gB named ping-pong; z zn->zc copy).
// Wave tile 128M x 64N: B bytes/step halved vs 64x128; wn-paired waves read
// identical B lines (L1 reuse). B loads are 1KB single-segment dwordx4 from
// frag-ordered fs2. Block 256 thr = 4 waves = 256M x 128N tile.
// Grid: 8 mtiles x 2 nblk x 32 K-chunks (28 slabs) = 512 blocks, XCD-swizzled.
#define HALF_GEN_MFMA(U0, gx0, gx1, bfX)                                   \
  {                                                                        \
    short8 af[4];                                                          \
    _Pragma("unroll") for (int uu = 0; uu < 4; ++uu) {                     \
      float zu = zc[U0 + uu];                                              \
      union { uint4 q; short8 s8; } pk;                                    \
      pk.q.x = pk_trunc(fmaxf(zu - gx0.x, 0.f), fmaxf(zu - gx0.y, 0.f));   \
      pk.q.y = pk_trunc(fmaxf(zu - gx0.z, 0.f), fmaxf(zu - gx0.w, 0.f));   \
      pk.q.z = pk_trunc(fmaxf(zu - gx1.x, 0.f), fmaxf(zu - gx1.y, 0.f));   \
      pk.q.w = pk_trunc(fmaxf(zu - gx1.z, 0.f), fmaxf(zu - gx1.w, 0.f));   \
      af[uu] = pk.s8;                                                      \
    }                                                                      \
    _Pragma("unroll") for (int uu = 0; uu < 4; ++uu)                       \
      _Pragma("unroll") for (int tt = 0; tt < 4; ++tt)                     \
        acc[U0 + uu][tt] = __builtin_amdgcn_mfma_f32_16x16x32_bf16(        \
            af[uu], bfX[tt], acc[U0 + uu][tt], 0, 0, 0);                   \
  }

#define KS_BODY(bfCur, bfNxt, gC0, gC1, gN0, gN1, sN, ksN)                 \
  {                                                                        \
    const char* bsrc = bB + (size_t)(sN) * 65536 + (ksN) * 8192;           \
    bfNxt[0] = *(const short8*)(bsrc);                                     \
    bfNxt[1] = *(const short8*)(bsrc + 1024);                              \
    bfNxt[2] = *(const short8*)(bsrc + 2048);                              \
    bfNxt[3] = *(const short8*)(bsrc + 3072);                              \
    const float* gp = gG + (size_t)(sN) * GRIDN + (ksN) * 32;              \
    gN0 = *(const float4*)gp;                                              \
    gN1 = *(const float4*)(gp + 4);                                        \
    HALF_GEN_MFMA(0, gC0, gC1, bfCur)                                      \
    HALF_GEN_MFMA(4, gC0, gC1, bfCur)                                      \
  }

__launch_bounds__(256, 2)
__global__ void gemm_kernel(const float* __restrict__ z_t,
                            const float* __restrict__ grids,
                            const __hip_bfloat16* __restrict__ fs2,
                            float* __restrict__ h_pre) {
  int bx = blockIdx.x;
  int xcd = bx & 7;
  int t6 = bx >> 3;                 // [0,64)
  int cg = t6 >> 4;                 // [0,4)
  int rem = t6 & 15;
  int mtile = rem >> 1;             // [0,8)  256-row tile
  int nblk = rem & 1;               // [0,2)  128-col half
  int chunk = xcd + 8 * cg;         // [0,32); same-XCD blocks share fs2 chunk
  int slab0 = chunk * 28;

  int tid = threadIdx.x;
  int w = tid >> 6, l = tid & 63;
  int l15 = l & 15, l4 = l >> 4;
  int wm = w >> 1, wn = w & 1;
  int mbase = mtile * 256 + wm * 128;

  floatx4 acc[8][4];
#pragma unroll
  for (int a = 0; a < 8; ++a)
#pragma unroll
    for (int b = 0; b < 4; ++b) acc[a][b] = (floatx4)0.f;

  const char* bB = (const char*)fs2 + (size_t)slab0 * 65536 +
                   (size_t)nblk * 32768 + (size_t)wn * 4096 + (size_t)l * 16;
  const float* gG = grids + (size_t)slab0 * GRIDN + l4 * 8;

  short8 bfA[4], bfB[4];
  float4 gA0, gA1, gB0, gB1;
  float zc[8], zn[8];

  // preload (s=0, ks=0)
  bfA[0] = *(const short8*)(bB);
  bfA[1] = *(const short8*)(bB + 1024);
  bfA[2] = *(const short8*)(bB + 2048);
  bfA[3] = *(const short8*)(bB + 3072);
  gA0 = *(const float4*)(gG);
  gA1 = *(const float4*)(gG + 4);
  {
    int iz = slab0 & 127;
    const float* zp = z_t + (size_t)iz * BATCH + mbase + l15;
#pragma unroll
    for (int u = 0; u < 8; ++u) zc[u] = zp[u * 16];
  }

#pragma unroll 1
  for (int s = 0; s < 28; ++s) {
    int sn = (s + 1 < 28) ? s + 1 : 27;
    {  // prefetch next slab's z rows (used next iteration)
      int iz = (slab0 + sn) & 127;
      const float* zp = z_t + (size_t)iz * BATCH + mbase + l15;
#pragma unroll
      for (int u = 0; u < 8; ++u) zn[u] = zp[u * 16];
    }
    KS_BODY(bfA, bfB, gA0, gA1, gB0, gB1, s, 1)
    KS_BODY(bfB, bfA, gB0, gB1, gA0, gA1, s, 2)
    KS_BODY(bfA, bfB, gA0, gA1, gB0, gB1, s, 3)
    KS_BODY(bfB, bfA, gB0, gB1, gA0, gA1, sn, 0)
#pragma unroll
    for (int u = 0; u < 8; ++u) zc[u] = zn[u];
  }

  // epilogue: atomic accumulate (C/D: col=l&15, row=(l>>4)*4+r)
  int row0 = mbase + l4 * 4;
  int col0 = nblk * 128 + wn * 64 + l15;
#pragma unroll
  for (int u = 0; u < 8; ++u) {
#pragma unroll
    for (int tt = 0; tt < 4; ++tt) {
      int col = col0 + tt * 16;
#pragma unroll
      for (int r = 0; r < 4; ++r) {
        int row = row0 + u * 16 + r;
        atomicAdd(&h_pre[(size_t)row * HID + col], acc[u][tt][r]);
      }
    }
  }
}

// ---------------- MLP layer: Y = act(X) @ W + b, col stats of Y ----------------
template <int FIRST>
__global__ void mlp_kernel(const float* __restrict__ Xin,
                           const float* __restrict__ statsIn,
                           const float* __restrict__ gamma,
                           const float* __restrict__ beta,
                           const float* __restrict__ W,
                           const float* __restrict__ bias,
                           float* __restrict__ Yout,
                           float* __restrict__ statsOut) {
  __shared__ float Xs[4][HID];
  int br = blockIdx.x, c = threadIdx.x;
  float mean = 0.f, rstd = 1.f, gm = 1.f, bt = 0.f;
  if (!FIRST) {
    float s1 = statsIn[c], s2 = statsIn[HID + c];
    mean = s1 * (1.0f / BATCH);
    float var = s2 * (1.0f / BATCH) - mean * mean;
    rstd = rsqrtf(var + 1e-5f);
    gm = gamma[c]; bt = beta[c];
  }
#pragma unroll
  for (int r = 0; r < 4; ++r) {
    float v = Xin[(size_t)(br * 4 + r) * HID + c];
    if (!FIRST) v = gelu_exact((v - mean) * rstd * gm + bt);
    Xs[r][c] = v;
  }
  __syncthreads();
  float acc[4] = {0, 0, 0, 0};
#pragma unroll 8
  for (int k = 0; k < HID; ++k) {
    float wv = W[(size_t)k * HID + c];
#pragma unroll
    for (int r = 0; r < 4; ++r) acc[r] += Xs[r][k] * wv;
  }
  float bb = bias[c];
  float s1 = 0.f, s2 = 0.f;
#pragma unroll
  for (int r = 0; r < 4; ++r) {
    float y = acc[r] + bb;
    Yout[(size_t)(br * 4 + r) * HID + c] = y;
    s1 += y; s2 += y * y;
  }
  atomicAdd(&statsOut[c], s1);
  atomicAdd(&statsOut[HID + c], s2);
}

// ---------------- final: out = gelu(bn(Y3)) @ W_out + b_out ----------------
__global__ void final_kernel(const float* __restrict__ Y3,
                             const float* __restrict__ statsIn,
                             const float* __restrict__ gamma,
                             const float* __restrict__ beta,
                             const float* __restrict__ W_out,
                             const float* __restrict__ b_out,
                             float* __restrict__ out) {
  int w = threadIdx.x >> 6, l = threadIdx.x & 63;
  int b = blockIdx.x * 4 + w;
  float4 y = *(const float4*)(Y3 + (size_t)b * HID + l * 4);
  float4 wv = *(const float4*)(W_out + l * 4);
  float r4[4] = {y.x, y.y, y.z, y.w};
  float w4[4] = {wv.x, wv.y, wv.z, wv.w};
  float s = 0.f;
  int c0 = l * 4;
#pragma unroll
  for (int q = 0; q < 4; ++q) {
    int c = c0 + q;
    float s1 = statsIn[c], s2 = statsIn[HID + c];
    float mean = s1 * (1.0f / BATCH);
    float var = s2 * (1.0f / BATCH) - mean * mean;
    float rstd = rsqrtf(var + 1e-5f);
    float v = gelu_exact((r4[q] - mean) * rstd * gamma[c] + beta[c]);
    s += v * w4[q];
  }
#pragma unroll
  for (int off = 32; off > 0; off >>= 1) s += __shfl_down(s, off);
  if (l == 0) out[b] = s + b_out[0];
}

extern "C" void kernel_launch(void* const* d_in, const int* in_sizes, int n_in,
                              void* d_out, int out_size, void* d_ws, size_t ws_size,
                              hipStream_t stream) {
  const float* x      = (const float*)d_in[0];
  const float* grids  = (const float*)d_in[1];
  const float* fs     = (const float*)d_in[2];
  const float* dscore = (const float*)d_in[3];
  const float* mlp_W  = (const float*)d_in[4];
  const float* mlp_b  = (const float*)d_in[5];
  const float* bn_g   = (const float*)d_in[6];
  const float* bn_b   = (const float*)d_in[7];
  const float* W_out  = (const float*)d_in[8];
  const float* b_out  = (const float*)d_in[9];
  float* out = (float*)d_out;

  char* ws = (char*)d_ws;
  __hip_bfloat16* fs2 = (__hip_bfloat16*)(ws + OFF_FST);
  float* z_t   = (float*)(ws + OFF_ZT);
  float* h_pre = (float*)(ws + OFF_HPRE);
  float* stats = (float*)(ws + OFF_STATS);
  u32*   keys  = (u32*)(ws + OFF_KEYS);
  float* cw    = (float*)(ws + OFF_CW);
  // Y buffers reuse the fs2 region (fs2 is dead after gemm; Y needed after)
  float* Y1    = (float*)(ws + OFF_FST);
  float* Y2    = (float*)(ws + OFF_FST + SZ_HPRE);
  float* Y3    = (float*)(ws + OFF_FST + 2 * SZ_HPRE);

  // zero the atomic accumulators (h_pre + BN stats + minmax keys)
  hipMemsetAsync(h_pre, 0, SZ_HPRE + SZ_STATS + SZ_KEYS, stream);

  prep1_kernel<<<64, 256, 0, stream>>>(x, keys, dscore, cw);
  prep2_kernel<<<32, 256, 0, stream>>>(x, keys, z_t);
  convert_kernel<<<DEPTH * IN_DIM, 256, 0, stream>>>(fs, cw, fs2);
  gemm_kernel<<<512, 256, 0, stream>>>(z_t, grids, fs2, h_pre);

  mlp_kernel<1><<<512, 256, 0, stream>>>(h_pre, nullptr, nullptr, nullptr,
                                         mlp_W, mlp_b, Y1, stats);
  mlp_kernel<0><<<512, 256, 0, stream>>>(Y1, stats, bn_g, bn_b,
                                         mlp_W + 65536, mlp_b + 256, Y2, stats + 512);
  mlp_kernel<0><<<512, 256, 0, stream>>>(Y2, stats + 512, bn_g + 256, bn_b + 256,
                                         mlp_W + 2 * 65536, mlp_b + 2 * 256, Y3, stats + 1024);
  final_kernel<<<512, 256, 0, stream>>>(Y3, stats + 1024, bn_g + 512, bn_b + 512,
                                        W_out, b_out, out);
}